// Round 1
// baseline (230.560 us; speedup 1.0000x reference)
//
#include <hip/hip_runtime.h>

#define BATCH 8192
#define IN_F 4096
#define OUT_F 4096

typedef float f4 __attribute__((ext_vector_type(4)));

// ---------------- Kernel 1: row sums, one wave (64 lanes) per row ----------
// No __syncthreads, no LDS: pure read stream + in-wave shuffle reduce.
// 8192 rows / 4 waves per block = 2048 blocks.
__global__ __launch_bounds__(256) void
rowsum_kernel(const float* __restrict__ x, float* __restrict__ rs) {
    const int wave = threadIdx.x >> 6;
    const int lane = threadIdx.x & 63;
    const int row  = (blockIdx.x << 2) + wave;

    const f4* x4 = reinterpret_cast<const f4*>(x + (size_t)row * IN_F);

    // 4096 floats = 1024 f4; 64 lanes x 16 f4 each, fully coalesced:
    // iteration j covers a contiguous 1 KiB segment.
    float s = 0.f;
#pragma unroll
    for (int j = 0; j < 16; ++j) {
        f4 v = x4[j * 64 + lane];
        s += (v.x + v.y) + (v.z + v.w);
    }

    // wave-64 shuffle reduction (no cross-wave communication needed)
#pragma unroll
    for (int off = 32; off > 0; off >>= 1)
        s += __shfl_down(s, off, 64);

    if (lane == 0) rs[row] = s;
}

// ---------------- Kernel 2: out[row,:] = rs[row] * w[:] --------------------
// Pure write stream. rs[row] is wave-uniform (scalar load); w is L1-hot.
// Nontemporal stores: out is never re-read, don't let it evict x from L2/L3.
__global__ __launch_bounds__(256) void
scale_kernel(const float* __restrict__ rs, const float* __restrict__ w,
             float* __restrict__ out) {
    const int row = blockIdx.x;
    const int tid = threadIdx.x;

    const float r = rs[row];

    const f4* w4 = reinterpret_cast<const f4*>(w);
    f4* o4 = reinterpret_cast<f4*>(out + (size_t)row * OUT_F);

#pragma unroll
    for (int j = 0; j < 4; ++j) {
        f4 wv = w4[j * 256 + tid];
        f4 ov;
        ov.x = r * wv.x;
        ov.y = r * wv.y;
        ov.z = r * wv.z;
        ov.w = r * wv.w;
        __builtin_nontemporal_store(ov, &o4[j * 256 + tid]);
    }
}

extern "C" void kernel_launch(void* const* d_in, const int* in_sizes, int n_in,
                              void* d_out, int out_size, void* d_ws, size_t ws_size,
                              hipStream_t stream) {
    const float* x = (const float*)d_in[0];   // [8192, 4096] fp32
    const float* w = (const float*)d_in[1];   // [1, 4096] fp32
    float* out = (float*)d_out;               // [8192, 4096] fp32
    float* rs = (float*)d_ws;                 // 8192 floats = 32 KiB workspace

    rowsum_kernel<<<BATCH / 4, 256, 0, stream>>>(x, rs);
    scale_kernel<<<BATCH, 256, 0, stream>>>(rs, w, out);
}

// Round 2
// 217.678 us; speedup vs baseline: 1.0592x; 1.0592x over previous
//
#include <hip/hip_runtime.h>

#define BATCH 8192
#define IN_F 4096
#define OUT_F 4096

typedef float f4 __attribute__((ext_vector_type(4)));

// ---------------- Kernel 1: row sums, one wave (64 lanes) per row ----------
// Pure read stream. Nontemporal loads: x is read exactly once per iteration
// and the L3 is full of poison-fill data — bypassing allocation avoids the
// read-miss-evict tax and L3 pollution.
__global__ __launch_bounds__(256) void
rowsum_kernel(const float* __restrict__ x, float* __restrict__ rs) {
    const int wave = threadIdx.x >> 6;
    const int lane = threadIdx.x & 63;
    const int row  = (blockIdx.x << 2) + wave;

    const f4* x4 = reinterpret_cast<const f4*>(x + (size_t)row * IN_F);

    // 4096 floats = 1024 f4; 64 lanes x 16 f4, each j covers contiguous 1 KiB.
    // 4 independent accumulators: no dependent-add chain between loads.
    float s0 = 0.f, s1 = 0.f, s2 = 0.f, s3 = 0.f;
#pragma unroll
    for (int j = 0; j < 16; j += 4) {
        f4 a = __builtin_nontemporal_load(&x4[(j + 0) * 64 + lane]);
        f4 b = __builtin_nontemporal_load(&x4[(j + 1) * 64 + lane]);
        f4 c = __builtin_nontemporal_load(&x4[(j + 2) * 64 + lane]);
        f4 d = __builtin_nontemporal_load(&x4[(j + 3) * 64 + lane]);
        s0 += (a.x + a.y) + (a.z + a.w);
        s1 += (b.x + b.y) + (b.z + b.w);
        s2 += (c.x + c.y) + (c.z + c.w);
        s3 += (d.x + d.y) + (d.z + d.w);
    }
    float s = (s0 + s1) + (s2 + s3);

    // wave-64 shuffle reduction (no cross-wave communication needed)
#pragma unroll
    for (int off = 32; off > 0; off >>= 1)
        s += __shfl_down(s, off, 64);

    if (lane == 0) rs[row] = s;
}

// ---------------- Kernel 2: out[row,:] = rs[row] * w[:] --------------------
// Pure write stream, fill-shaped (fill measures 6.7 TB/s on this box).
// rs[row] is wave-uniform; w (16 KiB) stays L1-hot. NT stores: out is never
// re-read, keep it out of L2/L3.
__global__ __launch_bounds__(256) void
scale_kernel(const float* __restrict__ rs, const float* __restrict__ w,
             float* __restrict__ out) {
    const int row = blockIdx.x;
    const int tid = threadIdx.x;

    const float r = rs[row];

    const f4* w4 = reinterpret_cast<const f4*>(w);
    f4* o4 = reinterpret_cast<f4*>(out + (size_t)row * OUT_F);

#pragma unroll
    for (int j = 0; j < 4; ++j) {
        f4 wv = w4[j * 256 + tid];
        f4 ov;
        ov.x = r * wv.x;
        ov.y = r * wv.y;
        ov.z = r * wv.z;
        ov.w = r * wv.w;
        __builtin_nontemporal_store(ov, &o4[j * 256 + tid]);
    }
}

extern "C" void kernel_launch(void* const* d_in, const int* in_sizes, int n_in,
                              void* d_out, int out_size, void* d_ws, size_t ws_size,
                              hipStream_t stream) {
    const float* x = (const float*)d_in[0];   // [8192, 4096] fp32
    const float* w = (const float*)d_in[1];   // [1, 4096] fp32
    float* out = (float*)d_out;               // [8192, 4096] fp32
    float* rs = (float*)d_ws;                 // 8192 floats = 32 KiB workspace

    rowsum_kernel<<<BATCH / 4, 256, 0, stream>>>(x, rs);
    scale_kernel<<<BATCH, 256, 0, stream>>>(rs, w, out);
}